// Round 1
// baseline (41.528 us; speedup 1.0000x reference)
//
#include <hip/hip_runtime.h>

namespace {
constexpr int H = 512;
constexpr int W = 512;
constexpr int NC = 96;               // 32 images * 3 channels (depthwise => independent planes)
constexpr int RSTRIP = 32;           // output rows per block
constexpr int NSTRIP = H / RSTRIP;   // 16
constexpr int NBLK = NC * NSTRIP;    // 1536 blocks
constexpr int NTHR = 256;            // 2 columns per thread
constexpr float INV_K2 = 1.0f / 49.0f;
constexpr float INV_TOTAL = 1.0f / (32.0f * 3.0f * 512.0f * 512.0f);
}

// Streams rows: d = pred - target staged in LDS per row; horizontal 7-sum from LDS;
// vertical 7-sum via a 7-deep register shift ring (static indices only).
__global__ __launch_bounds__(NTHR, 4) void lcl_partial(
    const float* __restrict__ pred, const float* __restrict__ target,
    float* __restrict__ partials)
{
    __shared__ __align__(16) float row_s[W + 8];   // [4 .. 515] data, [1..3] & [516..519] zero pads
    __shared__ float wred[NTHR / 64];

    const int tid   = threadIdx.x;
    const int img   = blockIdx.x / NSTRIP;
    const int strip = blockIdx.x - img * NSTRIP;
    const int y0    = strip * RSTRIP;
    const int c0    = tid * 2;
    const size_t base = (size_t)img * (size_t)(H * W);

    if (tid < 4) { row_s[tid] = 0.0f; row_s[W + 4 + tid] = 0.0f; }

    float2 hring[7];   // hring[i] = horizontal 7-sum of row (y - i)
    float2 dring[4];   // dring[i] = d at row (y - i)
#pragma unroll
    for (int i = 0; i < 7; ++i) hring[i] = make_float2(0.f, 0.f);
#pragma unroll
    for (int i = 0; i < 4; ++i) dring[i] = make_float2(0.f, 0.f);

    float acc = 0.0f;

    for (int y = y0 - 3; y < y0 + RSTRIP + 3; ++y) {
        float2 v = make_float2(0.f, 0.f);
        if ((unsigned)y < (unsigned)H) {
            const size_t roff = base + (size_t)y * W + c0;
            const float2 a = *(const float2*)(pred + roff);
            const float2 b = *(const float2*)(target + roff);
            v.x = a.x - b.x;
            v.y = a.y - b.y;
        }
        __syncthreads();                       // protect previous iteration's LDS reads
        *(float2*)&row_s[4 + c0] = v;          // byte offset (4+2t)*4 = 16+8t, 8B aligned
        __syncthreads();

        // horizontal 7-sums for columns c0 and c0+1: need row_s[c0+1 .. c0+8]
        const float w0 = row_s[c0 + 1];
        const float w1 = row_s[c0 + 2];
        const float w2 = row_s[c0 + 3];
        const float w3 = row_s[c0 + 4];
        const float w4 = row_s[c0 + 5];
        const float w5 = row_s[c0 + 6];
        const float w6 = row_s[c0 + 7];
        const float w7 = row_s[c0 + 8];
        const float hx = ((w0 + w1) + (w2 + w3)) + ((w4 + w5) + w6);
        const float hy = ((w1 + w2) + (w3 + w4)) + ((w5 + w6) + w7);

#pragma unroll
        for (int i = 6; i > 0; --i) hring[i] = hring[i - 1];
        hring[0] = make_float2(hx, hy);
#pragma unroll
        for (int i = 3; i > 0; --i) dring[i] = dring[i - 1];
        dring[0] = v;

        if (y >= y0 + 3) {                     // output row r = y - 3 in [y0, y0+RSTRIP)
            const float vsx = ((hring[0].x + hring[1].x) + (hring[2].x + hring[3].x))
                            + ((hring[4].x + hring[5].x) + hring[6].x);
            const float vsy = ((hring[0].y + hring[1].y) + (hring[2].y + hring[3].y))
                            + ((hring[4].y + hring[5].y) + hring[6].y);
            const float ox = dring[3].x - vsx * INV_K2;
            const float oy = dring[3].y - vsy * INV_K2;
            acc += fabsf(ox) + fabsf(oy);
        }
    }

    // wave (64-lane) reduce, then block reduce
#pragma unroll
    for (int off = 32; off > 0; off >>= 1)
        acc += __shfl_down(acc, off, 64);
    if ((tid & 63) == 0) wred[tid >> 6] = acc;
    __syncthreads();
    if (tid == 0)
        partials[blockIdx.x] = (wred[0] + wred[1]) + (wred[2] + wred[3]);
}

__global__ __launch_bounds__(256) void lcl_reduce(const float* __restrict__ partials,
                                                  float* __restrict__ out)
{
    __shared__ float wred[4];
    const int tid = threadIdx.x;
    float s = 0.0f;
    for (int i = tid; i < NBLK; i += 256) s += partials[i];
#pragma unroll
    for (int off = 32; off > 0; off >>= 1)
        s += __shfl_down(s, off, 64);
    if ((tid & 63) == 0) wred[tid >> 6] = s;
    __syncthreads();
    if (tid == 0) out[0] = ((wred[0] + wred[1]) + (wred[2] + wred[3])) * INV_TOTAL;
}

extern "C" void kernel_launch(void* const* d_in, const int* in_sizes, int n_in,
                              void* d_out, int out_size, void* d_ws, size_t ws_size,
                              hipStream_t stream) {
    const float* pred   = (const float*)d_in[0];
    const float* target = (const float*)d_in[1];
    float* out      = (float*)d_out;
    float* partials = (float*)d_ws;   // NBLK floats = 6 KB, well within ws

    lcl_partial<<<NBLK, NTHR, 0, stream>>>(pred, target, partials);
    lcl_reduce<<<1, 256, 0, stream>>>(partials, out);
}